// Round 1
// baseline (14149.481 us; speedup 1.0000x reference)
//
#include <hip/hip_runtime.h>
#include <math.h>

// NeRF fused volume renderer, MI355X (gfx950).
// Scheme B: one wave (64 lanes) per ray; lane = sample within a 64-sample batch;
// 2 batches cover S=128. MLP fully unrolled per lane (register arrays, constant
// indices only); weights staged to LDS, read as uniform-broadcast float4.
// Compositing: wave inclusive scan + carry; final __shfl_xor reductions.

#define NS 128
#define HDIM 64

static constexpr float STEPf = 0.040594940802395566f; // 3*sqrt(3)/128, rounded to f32

extern "C" __global__ void __launch_bounds__(256, 2)
nerf_render(const float* __restrict__ rays_o,
            const float* __restrict__ viewdirs,
            const void*  __restrict__ occ,
            const float* __restrict__ W1, const float* __restrict__ b1,
            const float* __restrict__ W2, const float* __restrict__ b2,
            const float* __restrict__ Ws, const float* __restrict__ bs,
            const float* __restrict__ Wc, const float* __restrict__ Wd,
            const float* __restrict__ bc, const float* __restrict__ Wr,
            const float* __restrict__ br,
            float* __restrict__ out, int nrays)
{
    // ---------------- LDS: weights (transposed for contiguous i-reads per j) ----
    __shared__ __align__(16) float sW1T[64 * 28];   // sW1T[j*28+i] = W1[i*64+j], [27]=0 pad
    __shared__ __align__(16) float sW2T[64 * 64];   // sW2T[j*64+i] = W2[i*64+j]
    __shared__ __align__(16) float sWcT[64 * 64];   // sWcT[j*64+i] = Wc[i*64+j]
    __shared__ __align__(16) float sWd [15 * 64];   // natural layout
    __shared__ __align__(16) float sWs [64];
    __shared__ __align__(16) float sWrT[3 * 64];    // sWrT[c*64+j] = Wr[j*3+c]
    __shared__ __align__(16) float sB1[64], sB2[64], sBc[64];
    __shared__ __align__(16) float sPdB[4][64];     // per-wave: (pe_d@Wd)[j] + bc[j]
    __shared__ int sKind;                           // occ dtype: 0=u8, 1=i32, 2=f32

    const int tid = threadIdx.x;

    // ---------------- stage weights ----------------
    for (int x = tid; x < 27 * 64; x += 256) {
        const int i = x >> 6, j = x & 63;
        sW1T[j * 28 + i] = W1[x];
    }
    for (int x = tid; x < 64 * 64; x += 256) {
        const int i = x >> 6, j = x & 63;
        sW2T[j * 64 + i] = W2[x];
        sWcT[j * 64 + i] = Wc[x];
    }
    for (int x = tid; x < 15 * 64; x += 256) sWd[x] = Wd[x];
    if (tid < 64) {
        sW1T[tid * 28 + 27] = 0.f;
        sB1[tid] = b1[tid];
        sB2[tid] = b2[tid];
        sBc[tid] = bc[tid];
        sWs[tid] = Ws[tid];
    }
    for (int x = tid; x < 192; x += 256) {
        const int j = x / 3, c = x - 3 * j;
        sWrT[c * 64 + j] = Wr[x];
    }
    if (tid == 0) {
        // sniff occ dtype from first 64 elements
        const int*   oi = (const int*)occ;
        const float* of = (const float*)occ;
        bool i32ok = true, f32ok = true;
        for (int k = 0; k < 64; ++k) {
            const int v = oi[k];
            if (v != 0 && v != 1) i32ok = false;
            const float f = of[k];
            if (!(f == 0.f || f == 1.f)) f32ok = false;
        }
        sKind = i32ok ? 1 : (f32ok ? 2 : 0);
    }
    __syncthreads();

    const int lane = tid & 63;
    const int wib  = tid >> 6;
    const int ray  = (blockIdx.x << 2) | wib;
    if (ray >= nrays) return;
    const int kind = sKind;

    // ---------------- ray setup ----------------
    const float ox = rays_o[ray * 3 + 0], oy = rays_o[ray * 3 + 1], oz = rays_o[ray * 3 + 2];
    const float dxv = viewdirs[ray * 3 + 0], dyv = viewdirs[ray * 3 + 1], dzv = viewdirs[ray * 3 + 2];

    const float sdx = fabsf(dxv) < 1e-8f ? 1e-8f : dxv;
    const float sdy = fabsf(dyv) < 1e-8f ? 1e-8f : dyv;
    const float sdz = fabsf(dzv) < 1e-8f ? 1e-8f : dzv;
    const float t1x = (-1.5f - ox) / sdx, t2x = (1.5f - ox) / sdx;
    const float t1y = (-1.5f - oy) / sdy, t2y = (1.5f - oy) / sdy;
    const float t1z = (-1.5f - oz) / sdz, t2z = (1.5f - oz) / sdz;
    const float t_near = fmaxf(fmaxf(fminf(t1x, t2x), fminf(t1y, t2y)),
                               fmaxf(fminf(t1z, t2z), 0.f));
    const float t_far  = fminf(fminf(fmaxf(t1x, t2x), fmaxf(t1y, t2y)), fmaxf(t1z, t2z));

    // per-ray dir posenc -> pd[j] + bc[j] into LDS (lane j computes one output)
    {
        float ped[15];
        ped[0] = dxv; ped[1] = dyv; ped[2] = dzv;
        const float dc[3] = {dxv, dyv, dzv};
        #pragma unroll
        for (int c = 0; c < 3; ++c) {
            ped[3 + c * 4 + 0] = __sinf(dc[c]);
            ped[3 + c * 4 + 1] = __sinf(dc[c] * 2.f);
            ped[3 + c * 4 + 2] = __cosf(dc[c]);
            ped[3 + c * 4 + 3] = __cosf(dc[c] * 2.f);
        }
        float pd = 0.f;
        #pragma unroll
        for (int i = 0; i < 15; ++i) pd += ped[i] * sWd[i * 64 + lane];
        sPdB[wib][lane] = pd + sBc[lane];
    }

    const float bsV = bs[0];
    const float br0 = br[0], br1 = br[1], br2 = br[2];

    float carry = 0.f;
    float aW = 0.f, aWT = 0.f, aR = 0.f, aG = 0.f, aB = 0.f;

    #pragma unroll 1
    for (int b = 0; b < 2; ++b) {
        const int sIdx = (b << 6) | lane;
        const float t = t_near + ((float)sIdx + 0.5f) * STEPf;
        const bool in_seg = t < t_far;
        if (__ballot(in_seg) == 0ULL) break;   // samples monotone in t: done

        const float px = ox + dxv * t, py = oy + dyv * t, pz = oz + dzv * t;
        const float cx = (px + 1.5f) * (128.f / 3.f);
        const float cy = (py + 1.5f) * (128.f / 3.f);
        const float cz = (pz + 1.5f) * (128.f / 3.f);
        const bool in_box = (cx >= 0.f) & (cx < 128.f) & (cy >= 0.f) & (cy < 128.f)
                          & (cz >= 0.f) & (cz < 128.f);
        const int ix = min(max((int)floorf(cx), 0), 127);
        const int iy = min(max((int)floorf(cy), 0), 127);
        const int iz = min(max((int)floorf(cz), 0), 127);
        const int ci = (ix << 14) | (iy << 7) | iz;
        bool occv;
        if (kind == 1)      occv = ((const int*)occ)[ci] != 0;
        else if (kind == 2) occv = ((const float*)occ)[ci] != 0.f;
        else                occv = ((const unsigned char*)occ)[ci] != 0;
        const bool valid = in_seg & in_box & occv;

        if (__ballot(valid) != 0ULL) {
            // ---- posenc(pts, L=4): 27 features (+1 zero pad) ----
            float pe[28];
            pe[0] = px; pe[1] = py; pe[2] = pz; pe[27] = 0.f;
            const float pc[3] = {px, py, pz};
            #pragma unroll
            for (int c = 0; c < 3; ++c) {
                float f = 1.f;
                #pragma unroll
                for (int l = 0; l < 4; ++l) {
                    pe[3 + c * 8 + l]     = __sinf(pc[c] * f);
                    pe[3 + c * 8 + 4 + l] = __cosf(pc[c] * f);
                    f *= 2.f;
                }
            }
            // ---- layer1: 28 -> 64 ----
            float h1[64];
            #pragma unroll
            for (int j = 0; j < 64; ++j) {
                float a = sB1[j];
                #pragma unroll
                for (int i = 0; i < 28; i += 4) {
                    const float4 w = *(const float4*)&sW1T[j * 28 + i];
                    a += w.x * pe[i] + w.y * pe[i + 1] + w.z * pe[i + 2] + w.w * pe[i + 3];
                }
                h1[j] = fmaxf(a, 0.f);
            }
            // ---- layer2: 64 -> 64 ----
            float h2[64];
            #pragma unroll
            for (int j = 0; j < 64; ++j) {
                float a = sB2[j];
                #pragma unroll
                for (int i = 0; i < 64; i += 4) {
                    const float4 w = *(const float4*)&sW2T[j * 64 + i];
                    a += w.x * h1[i] + w.y * h1[i + 1] + w.z * h1[i + 2] + w.w * h1[i + 3];
                }
                h2[j] = fmaxf(a, 0.f);
            }
            // ---- sigma head ----
            float sgv = bsV;
            #pragma unroll
            for (int i = 0; i < 64; i += 4) {
                const float4 w = *(const float4*)&sWs[i];
                sgv += w.x * h2[i] + w.y * h2[i + 1] + w.z * h2[i + 2] + w.w * h2[i + 3];
            }
            const float sigma = valid ? fmaxf(sgv, 0.f) : 0.f;
            // ---- color feature: 64 -> 64 (+ pd + bc) ----
            float gl[64];
            #pragma unroll
            for (int j = 0; j < 64; ++j) {
                float a = sPdB[wib][j];
                #pragma unroll
                for (int i = 0; i < 64; i += 4) {
                    const float4 w = *(const float4*)&sWcT[j * 64 + i];
                    a += w.x * h2[i] + w.y * h2[i + 1] + w.z * h2[i + 2] + w.w * h2[i + 3];
                }
                gl[j] = fmaxf(a, 0.f);
            }
            // ---- rgb head ----
            float cr = br0, cg = br1, cb = br2;
            #pragma unroll
            for (int i = 0; i < 64; i += 4) {
                const float4 w0 = *(const float4*)&sWrT[0 * 64 + i];
                const float4 w1 = *(const float4*)&sWrT[1 * 64 + i];
                const float4 w2 = *(const float4*)&sWrT[2 * 64 + i];
                cr += w0.x * gl[i] + w0.y * gl[i + 1] + w0.z * gl[i + 2] + w0.w * gl[i + 3];
                cg += w1.x * gl[i] + w1.y * gl[i + 1] + w1.z * gl[i + 2] + w1.w * gl[i + 3];
                cb += w2.x * gl[i] + w2.y * gl[i + 1] + w2.z * gl[i + 2] + w2.w * gl[i + 3];
            }
            const float rC = 1.f / (1.f + __expf(-cr));
            const float gC = 1.f / (1.f + __expf(-cg));
            const float bC = 1.f / (1.f + __expf(-cb));

            // ---- compositing: wave inclusive scan of sdelta ----
            const float sdelta = sigma * STEPf;
            float scan = sdelta;
            #pragma unroll
            for (int off = 1; off < 64; off <<= 1) {
                const float n = __shfl_up(scan, off);
                if (lane >= off) scan += n;
            }
            const float T     = __expf(-(carry + scan - sdelta));
            const float alpha = 1.f - __expf(-sdelta);
            const float w = T * alpha;
            aW  += w;
            aWT += w * t;
            aR  += w * rC;
            aG  += w * gC;
            aB  += w * bC;
            carry += __shfl(scan, 63);
            if (carry > 12.f) break;   // T < 6e-6: remaining contribution negligible
        }
    }

    // ---- reduce across lanes ----
    #pragma unroll
    for (int off = 32; off; off >>= 1) {
        aW  += __shfl_xor(aW,  off);
        aWT += __shfl_xor(aWT, off);
        aR  += __shfl_xor(aR,  off);
        aG  += __shfl_xor(aG,  off);
        aB  += __shfl_xor(aB,  off);
    }
    if (lane == 0) {
        const float bg = 1.f - aW;
        out[ray * 3 + 0] = aR + bg;
        out[ray * 3 + 1] = aG + bg;
        out[ray * 3 + 2] = aB + bg;
        out[3 * nrays + ray] = aWT;   // depth
        out[4 * nrays + ray] = aW;    // acc
    }
}

extern "C" void kernel_launch(void* const* d_in, const int* in_sizes, int n_in,
                              void* d_out, int out_size, void* d_ws, size_t ws_size,
                              hipStream_t stream) {
    const float* rays_o   = (const float*)d_in[0];
    const float* viewdirs = (const float*)d_in[1];
    const void*  occ      = (const void*) d_in[2];
    const float* W1 = (const float*)d_in[3];
    const float* b1 = (const float*)d_in[4];
    const float* W2 = (const float*)d_in[5];
    const float* b2 = (const float*)d_in[6];
    const float* Ws = (const float*)d_in[7];
    const float* bs = (const float*)d_in[8];
    const float* Wc = (const float*)d_in[9];
    const float* Wd = (const float*)d_in[10];
    const float* bc = (const float*)d_in[11];
    const float* Wr = (const float*)d_in[12];
    const float* br = (const float*)d_in[13];
    float* out = (float*)d_out;

    const int nrays = in_sizes[0] / 3;
    const int nblocks = (nrays + 3) / 4;   // 4 rays (waves) per 256-thread block

    nerf_render<<<nblocks, 256, 0, stream>>>(rays_o, viewdirs, occ,
                                             W1, b1, W2, b2, Ws, bs, Wc, Wd, bc, Wr, br,
                                             out, nrays);
}

// Round 2
// 12640.086 us; speedup vs baseline: 1.1194x; 1.1194x over previous
//
#include <hip/hip_runtime.h>
#include <math.h>

// NeRF fused volume renderer, MI355X (gfx950).
// Lane = sample (64 samples/batch, 2 batches = S=128), wave = ray, 4 rays/block.
// Round 2: spill-free restructure —
//   * color layer fused with rgb head (no gl[64] array)
//   * sigma head fused into L2 loop
//   * peak live regs ~155 (h1[64]+h2[64]+scalars), launch_bounds(256,3) -> cap 170
//   * posenc via double-angle recurrence: 6 transcendentals/sample instead of 24
// Weights staged in LDS, read as uniform-address (broadcast, conflict-free) float4.

static constexpr float STEPf = 0.040594940802395566f; // 3*sqrt(3)/128 in f32

extern "C" __global__ void __launch_bounds__(256, 3)
nerf_render(const float* __restrict__ rays_o,
            const float* __restrict__ viewdirs,
            const void*  __restrict__ occ,
            const float* __restrict__ W1, const float* __restrict__ b1,
            const float* __restrict__ W2, const float* __restrict__ b2,
            const float* __restrict__ Ws, const float* __restrict__ bs,
            const float* __restrict__ Wc, const float* __restrict__ Wd,
            const float* __restrict__ bc, const float* __restrict__ Wr,
            const float* __restrict__ br,
            float* __restrict__ out, int nrays)
{
    __shared__ __align__(16) float sW1T[64 * 28];   // sW1T[j*28+i] = W1[i*64+j], [27]=0 pad
    __shared__ __align__(16) float sW2T[64 * 64];   // sW2T[j*64+i] = W2[i*64+j]
    __shared__ __align__(16) float sWcT[64 * 64];   // sWcT[j*64+i] = Wc[i*64+j]
    __shared__ __align__(16) float sWs [64];
    __shared__ __align__(16) float4 sWr4[64];       // sWr4[j] = (Wr[j][0..2], 0)
    __shared__ __align__(16) float sB1[64], sB2[64];
    __shared__ __align__(16) float sPdB[4][64];     // per-wave: (pe_d@Wd)[j] + bc[j]
    __shared__ int sKind;                           // occ dtype: 0=u8, 1=i32, 2=f32

    const int tid = threadIdx.x;

    // ---------------- stage weights ----------------
    for (int x = tid; x < 27 * 64; x += 256) {
        const int i = x >> 6, j = x & 63;
        sW1T[j * 28 + i] = W1[x];
    }
    for (int x = tid; x < 64 * 64; x += 256) {
        const int i = x >> 6, j = x & 63;
        sW2T[j * 64 + i] = W2[x];
        sWcT[j * 64 + i] = Wc[x];
    }
    if (tid < 64) {
        sW1T[tid * 28 + 27] = 0.f;
        sB1[tid] = b1[tid];
        sB2[tid] = b2[tid];
        sWs[tid] = Ws[tid];
        sWr4[tid] = make_float4(Wr[tid * 3 + 0], Wr[tid * 3 + 1], Wr[tid * 3 + 2], 0.f);
    }
    if (tid == 0) {
        const int*   oi = (const int*)occ;
        const float* of = (const float*)occ;
        bool i32ok = true, f32ok = true;
        for (int k = 0; k < 64; ++k) {
            const int v = oi[k];
            if (v != 0 && v != 1) i32ok = false;
            const float f = of[k];
            if (!(f == 0.f || f == 1.f)) f32ok = false;
        }
        sKind = i32ok ? 1 : (f32ok ? 2 : 0);
    }
    __syncthreads();

    const int lane = tid & 63;
    const int wib  = tid >> 6;
    const int ray  = (blockIdx.x << 2) | wib;
    if (ray >= nrays) return;
    const int kind = sKind;

    // ---------------- ray setup ----------------
    const float ox = rays_o[ray * 3 + 0], oy = rays_o[ray * 3 + 1], oz = rays_o[ray * 3 + 2];
    const float dxv = viewdirs[ray * 3 + 0], dyv = viewdirs[ray * 3 + 1], dzv = viewdirs[ray * 3 + 2];

    const float sdx = fabsf(dxv) < 1e-8f ? 1e-8f : dxv;
    const float sdy = fabsf(dyv) < 1e-8f ? 1e-8f : dyv;
    const float sdz = fabsf(dzv) < 1e-8f ? 1e-8f : dzv;
    const float t1x = (-1.5f - ox) / sdx, t2x = (1.5f - ox) / sdx;
    const float t1y = (-1.5f - oy) / sdy, t2y = (1.5f - oy) / sdy;
    const float t1z = (-1.5f - oz) / sdz, t2z = (1.5f - oz) / sdz;
    const float t_near = fmaxf(fmaxf(fminf(t1x, t2x), fminf(t1y, t2y)),
                               fmaxf(fminf(t1z, t2z), 0.f));
    const float t_far  = fminf(fminf(fmaxf(t1x, t2x), fmaxf(t1y, t2y)), fmaxf(t1z, t2z));

    // per-ray dir posenc -> pd[j] + bc[j] into LDS (lane j computes one output)
    {
        float ped[15];
        ped[0] = dxv; ped[1] = dyv; ped[2] = dzv;
        const float dc[3] = {dxv, dyv, dzv};
        #pragma unroll
        for (int c = 0; c < 3; ++c) {
            float s1, c1;
            __sincosf(dc[c], &s1, &c1);
            ped[3 + c * 4 + 0] = s1;
            ped[3 + c * 4 + 1] = 2.f * s1 * c1;          // sin 2x
            ped[3 + c * 4 + 2] = c1;
            ped[3 + c * 4 + 3] = 1.f - 2.f * s1 * s1;    // cos 2x
        }
        float pd = 0.f;
        #pragma unroll
        for (int i = 0; i < 15; ++i) pd += ped[i] * Wd[i * 64 + lane];
        sPdB[wib][lane] = pd + bc[lane];
    }

    const float bsV = bs[0];
    const float br0 = br[0], br1 = br[1], br2 = br[2];

    float carry = 0.f;
    float aW = 0.f, aWT = 0.f, aR = 0.f, aG = 0.f, aB = 0.f;

    #pragma unroll 1
    for (int b = 0; b < 2; ++b) {
        const int sIdx = (b << 6) | lane;
        const float t = t_near + ((float)sIdx + 0.5f) * STEPf;
        const bool in_seg = t < t_far;
        if (__ballot(in_seg) == 0ULL) break;   // samples monotone in t: done

        const float px = ox + dxv * t, py = oy + dyv * t, pz = oz + dzv * t;
        const float cx = (px + 1.5f) * (128.f / 3.f);
        const float cy = (py + 1.5f) * (128.f / 3.f);
        const float cz = (pz + 1.5f) * (128.f / 3.f);
        const bool in_box = (cx >= 0.f) & (cx < 128.f) & (cy >= 0.f) & (cy < 128.f)
                          & (cz >= 0.f) & (cz < 128.f);
        const int ix = min(max((int)floorf(cx), 0), 127);
        const int iy = min(max((int)floorf(cy), 0), 127);
        const int iz = min(max((int)floorf(cz), 0), 127);
        const int ci = (ix << 14) | (iy << 7) | iz;
        bool occv;
        if (kind == 1)      occv = ((const int*)occ)[ci] != 0;
        else if (kind == 2) occv = ((const float*)occ)[ci] != 0.f;
        else                occv = ((const unsigned char*)occ)[ci] != 0;
        const bool valid = in_seg & in_box & occv;

        if (__ballot(valid) != 0ULL) {
            // ---- posenc(pts, L=4): sin/cos of x,2x,4x,8x via double-angle ----
            float pe[28];
            pe[0] = px; pe[1] = py; pe[2] = pz; pe[27] = 0.f;
            const float pc[3] = {px, py, pz};
            #pragma unroll
            for (int c = 0; c < 3; ++c) {
                float s1, c1;
                __sincosf(pc[c], &s1, &c1);
                const float s2 = 2.f * s1 * c1, c2 = 1.f - 2.f * s1 * s1;
                const float s4 = 2.f * s2 * c2, c4 = 1.f - 2.f * s2 * s2;
                const float s8 = 2.f * s4 * c4, c8 = 1.f - 2.f * s4 * s4;
                pe[3 + c * 8 + 0] = s1; pe[3 + c * 8 + 1] = s2;
                pe[3 + c * 8 + 2] = s4; pe[3 + c * 8 + 3] = s8;
                pe[3 + c * 8 + 4] = c1; pe[3 + c * 8 + 5] = c2;
                pe[3 + c * 8 + 6] = c4; pe[3 + c * 8 + 7] = c8;
            }
            // ---- layer1: 28 -> 64 ----
            float h1[64];
            #pragma unroll
            for (int j = 0; j < 64; ++j) {
                float a = sB1[j];
                #pragma unroll
                for (int i = 0; i < 28; i += 4) {
                    const float4 w = *(const float4*)&sW1T[j * 28 + i];
                    a += w.x * pe[i] + w.y * pe[i + 1] + w.z * pe[i + 2] + w.w * pe[i + 3];
                }
                h1[j] = fmaxf(a, 0.f);
            }
            // ---- layer2 + sigma head fused: 64 -> 64, sigma = Ws . h2 ----
            float h2[64];
            float sgv = bsV;
            #pragma unroll
            for (int j = 0; j < 64; ++j) {
                float a = sB2[j];
                #pragma unroll
                for (int i = 0; i < 64; i += 4) {
                    const float4 w = *(const float4*)&sW2T[j * 64 + i];
                    a += w.x * h1[i] + w.y * h1[i + 1] + w.z * h1[i + 2] + w.w * h1[i + 3];
                }
                const float h2j = fmaxf(a, 0.f);
                h2[j] = h2j;
                sgv += sWs[j] * h2j;
            }
            const float sigma = valid ? fmaxf(sgv, 0.f) : 0.f;
            // ---- color layer fused with rgb head: g_j consumed immediately ----
            float cr = br0, cg = br1, cb = br2;
            #pragma unroll
            for (int j = 0; j < 64; ++j) {
                float a = sPdB[wib][j];
                #pragma unroll
                for (int i = 0; i < 64; i += 4) {
                    const float4 w = *(const float4*)&sWcT[j * 64 + i];
                    a += w.x * h2[i] + w.y * h2[i + 1] + w.z * h2[i + 2] + w.w * h2[i + 3];
                }
                const float g = fmaxf(a, 0.f);
                const float4 wr = sWr4[j];
                cr += wr.x * g; cg += wr.y * g; cb += wr.z * g;
            }
            const float rC = 1.f / (1.f + __expf(-cr));
            const float gC = 1.f / (1.f + __expf(-cg));
            const float bC = 1.f / (1.f + __expf(-cb));

            // ---- compositing: wave inclusive scan of sdelta ----
            const float sdelta = sigma * STEPf;
            float scan = sdelta;
            #pragma unroll
            for (int off = 1; off < 64; off <<= 1) {
                const float n = __shfl_up(scan, off);
                if (lane >= off) scan += n;
            }
            const float T     = __expf(-(carry + scan - sdelta));
            const float alpha = 1.f - __expf(-sdelta);
            const float w = T * alpha;
            aW  += w;
            aWT += w * t;
            aR  += w * rC;
            aG  += w * gC;
            aB  += w * bC;
            carry += __shfl(scan, 63);
            if (carry > 12.f) break;   // T < 6e-6: remaining contribution negligible
        }
    }

    // ---- reduce across lanes ----
    #pragma unroll
    for (int off = 32; off; off >>= 1) {
        aW  += __shfl_xor(aW,  off);
        aWT += __shfl_xor(aWT, off);
        aR  += __shfl_xor(aR,  off);
        aG  += __shfl_xor(aG,  off);
        aB  += __shfl_xor(aB,  off);
    }
    if (lane == 0) {
        const float bg = 1.f - aW;
        out[ray * 3 + 0] = aR + bg;
        out[ray * 3 + 1] = aG + bg;
        out[ray * 3 + 2] = aB + bg;
        out[3 * nrays + ray] = aWT;   // depth
        out[4 * nrays + ray] = aW;    // acc
    }
}

extern "C" void kernel_launch(void* const* d_in, const int* in_sizes, int n_in,
                              void* d_out, int out_size, void* d_ws, size_t ws_size,
                              hipStream_t stream) {
    const float* rays_o   = (const float*)d_in[0];
    const float* viewdirs = (const float*)d_in[1];
    const void*  occ      = (const void*) d_in[2];
    const float* W1 = (const float*)d_in[3];
    const float* b1 = (const float*)d_in[4];
    const float* W2 = (const float*)d_in[5];
    const float* b2 = (const float*)d_in[6];
    const float* Ws = (const float*)d_in[7];
    const float* bs = (const float*)d_in[8];
    const float* Wc = (const float*)d_in[9];
    const float* Wd = (const float*)d_in[10];
    const float* bc = (const float*)d_in[11];
    const float* Wr = (const float*)d_in[12];
    const float* br = (const float*)d_in[13];
    float* out = (float*)d_out;

    const int nrays = in_sizes[0] / 3;
    const int nblocks = (nrays + 3) / 4;   // 4 rays (waves) per 256-thread block

    nerf_render<<<nblocks, 256, 0, stream>>>(rays_o, viewdirs, occ,
                                             W1, b1, W2, b2, Ws, bs, Wc, Wd, bc, Wr, br,
                                             out, nrays);
}

// Round 3
// 76.077 us; speedup vs baseline: 185.9880x; 166.1477x over previous
//
#include <hip/hip_runtime.h>
#include <math.h>

// NeRF fused volume renderer, MI355X (gfx950) — MFMA edition.
// Wave = ray, batch = 64 samples (2 batches for S=128), lane&15 = sample-in-tile.
// MLP layers as mfma_f32_16x16x32_f16: D[h][s] = A(W^T) x B(activations).
// Activations round-trip through an 8KB/wave LDS buffer (X -> H1 -> H2 in place),
// XOR-swizzled to kill bank conflicts. Heads (sigma/rgb) on fragments in VALU.
// C/D layout (m89-verified): col = lane&15, row = (lane>>4)*4 + reg.
// A/B layout (standard):     row/col = lane&15, k = (lane>>4)*8 + e.

typedef _Float16 f16x8 __attribute__((ext_vector_type(8)));
typedef float f32x4 __attribute__((ext_vector_type(4)));

static constexpr float STEPf = 0.040594940802395566f; // 3*sqrt(3)/128 in f32

static __device__ __forceinline__ unsigned pk2(float a, float b) {
    return __builtin_bit_cast(unsigned, __builtin_amdgcn_cvt_pkrtz(a, b));
}

extern "C" __global__ void __launch_bounds__(256, 2)
nerf_mfma(const float* __restrict__ rays_o, const float* __restrict__ viewdirs,
          const void* __restrict__ occ,
          const float* __restrict__ W1g, const float* __restrict__ b1g,
          const float* __restrict__ W2g, const float* __restrict__ b2g,
          const float* __restrict__ Wsg, const float* __restrict__ bsg,
          const float* __restrict__ Wcg, const float* __restrict__ Wdg,
          const float* __restrict__ bcg, const float* __restrict__ Wrg,
          const float* __restrict__ brg,
          float* __restrict__ out, int nrays)
{
    // A-operand weights, f16, pre-transposed: sW[h][k], k-contiguous, XOR-swizzled.
    __shared__ __align__(16) unsigned char sW1[64 * 64];    // rows 64B  (K=32), swz (h&3)
    __shared__ __align__(16) unsigned char sW2[64 * 128];   // rows 128B (K=64), swz (h&7)
    __shared__ __align__(16) unsigned char sWc[64 * 128];
    __shared__ __align__(16) float sB1[64], sB2[64], sWs[64];
    __shared__ __align__(16) float sWrR[64], sWrG[64], sWrB[64];
    __shared__ __align__(16) float sPdB[4][64];             // per-wave (pe_d@Wd + bc)
    __shared__ __align__(16) unsigned char sAct[4][8192];   // per-wave activation buf
    __shared__ int sKind;

    const int tid = threadIdx.x;

    // ---------------- stage weights (f16, transposed, swizzled) ----------------
    for (int idx = tid; idx < 64 * 32; idx += 256) {        // W1: A[h][k]=W1[k][h], pad k>=27
        const int h = idx >> 5, k = idx & 31;
        const float v = (k < 27) ? W1g[k * 64 + h] : 0.f;
        *(_Float16*)(sW1 + h * 64 + (((k >> 3) ^ (h & 3)) << 4) + ((k & 7) << 1)) = (_Float16)v;
    }
    for (int idx = tid; idx < 64 * 64; idx += 256) {        // W2, Wc
        const int h = idx >> 6, k = idx & 63;
        const int off = h * 128 + (((k >> 3) ^ (h & 7)) << 4) + ((k & 7) << 1);
        *(_Float16*)(sW2 + off) = (_Float16)W2g[k * 64 + h];
        *(_Float16*)(sWc + off) = (_Float16)Wcg[k * 64 + h];
    }
    if (tid < 64) {
        sB1[tid] = b1g[tid]; sB2[tid] = b2g[tid]; sWs[tid] = Wsg[tid];
        sWrR[tid] = Wrg[tid * 3 + 0]; sWrG[tid] = Wrg[tid * 3 + 1]; sWrB[tid] = Wrg[tid * 3 + 2];
    }
    if (tid == 0) {   // sniff occ dtype: 0=u8, 1=i32, 2=f32
        const int*   oi = (const int*)occ;
        const float* of = (const float*)occ;
        bool i32ok = true, f32ok = true;
        for (int k = 0; k < 64; ++k) {
            if (oi[k] != 0 && oi[k] != 1) i32ok = false;
            const float f = of[k];
            if (!(f == 0.f || f == 1.f)) f32ok = false;
        }
        sKind = i32ok ? 1 : (f32ok ? 2 : 0);
    }
    __syncthreads();

    const int lane = tid & 63;
    const int wib  = tid >> 6;
    const int ray  = (blockIdx.x << 2) | wib;
    if (ray >= nrays) return;
    const int kind = sKind;
    const int lh = lane & 15, g = lane >> 4;
    unsigned char* const act = sAct[wib];

    // ---------------- ray setup ----------------
    const float ox = rays_o[ray * 3 + 0], oy = rays_o[ray * 3 + 1], oz = rays_o[ray * 3 + 2];
    const float dxv = viewdirs[ray * 3 + 0], dyv = viewdirs[ray * 3 + 1], dzv = viewdirs[ray * 3 + 2];
    const float sdx = fabsf(dxv) < 1e-8f ? 1e-8f : dxv;
    const float sdy = fabsf(dyv) < 1e-8f ? 1e-8f : dyv;
    const float sdz = fabsf(dzv) < 1e-8f ? 1e-8f : dzv;
    const float t1x = (-1.5f - ox) / sdx, t2x = (1.5f - ox) / sdx;
    const float t1y = (-1.5f - oy) / sdy, t2y = (1.5f - oy) / sdy;
    const float t1z = (-1.5f - oz) / sdz, t2z = (1.5f - oz) / sdz;
    const float t_near = fmaxf(fmaxf(fminf(t1x, t2x), fminf(t1y, t2y)),
                               fmaxf(fminf(t1z, t2z), 0.f));
    const float t_far  = fminf(fminf(fmaxf(t1x, t2x), fmaxf(t1y, t2y)), fmaxf(t1z, t2z));

    // per-ray dir posenc -> sPdB[wib][j] = (pe_d @ Wd)[j] + bc[j]
    {
        float ped[15];
        ped[0] = dxv; ped[1] = dyv; ped[2] = dzv;
        const float dc[3] = {dxv, dyv, dzv};
        #pragma unroll
        for (int c = 0; c < 3; ++c) {
            float s1, c1;
            __sincosf(dc[c], &s1, &c1);
            ped[3 + c * 4 + 0] = s1;
            ped[3 + c * 4 + 1] = 2.f * s1 * c1;
            ped[3 + c * 4 + 2] = c1;
            ped[3 + c * 4 + 3] = 1.f - 2.f * s1 * s1;
        }
        float pd = 0.f;
        #pragma unroll
        for (int i = 0; i < 15; ++i) pd += ped[i] * Wdg[i * 64 + lane];
        sPdB[wib][lane] = pd + bcg[lane];
    }

    const float bsV = bsg[0];
    const float br0 = brg[0], br1 = brg[1], br2 = brg[2];

    float carry = 0.f;
    float aW = 0.f, aWT = 0.f, aR = 0.f, aG = 0.f, aB = 0.f;

    #pragma unroll 1
    for (int b = 0; b < 2; ++b) {
        const int sIdx = (b << 6) | lane;
        const float t = t_near + ((float)sIdx + 0.5f) * STEPf;
        const bool in_seg = t < t_far;
        if (__ballot(in_seg) == 0ULL) break;

        const float px = ox + dxv * t, py = oy + dyv * t, pz = oz + dzv * t;
        const float cx = (px + 1.5f) * (128.f / 3.f);
        const float cy = (py + 1.5f) * (128.f / 3.f);
        const float cz = (pz + 1.5f) * (128.f / 3.f);
        const bool in_box = (cx >= 0.f) & (cx < 128.f) & (cy >= 0.f) & (cy < 128.f)
                          & (cz >= 0.f) & (cz < 128.f);
        const int ix = min(max((int)floorf(cx), 0), 127);
        const int iy = min(max((int)floorf(cy), 0), 127);
        const int iz = min(max((int)floorf(cz), 0), 127);
        const int ci = (ix << 14) | (iy << 7) | iz;
        bool occv;
        if (kind == 1)      occv = ((const int*)occ)[ci] != 0;
        else if (kind == 2) occv = ((const float*)occ)[ci] != 0.f;
        else                occv = ((const unsigned char*)occ)[ci] != 0;
        const bool valid = in_seg & in_box & occv;

        if (__ballot(valid) != 0ULL) {
            // ---- posenc -> X[lane][k] f16 in LDS (rows 64B, swz kc^(s&3)) ----
            float pe[28];
            pe[0] = px; pe[1] = py; pe[2] = pz; pe[27] = 0.f;
            const float pc[3] = {px, py, pz};
            #pragma unroll
            for (int c = 0; c < 3; ++c) {
                float s1, c1;
                __sincosf(pc[c], &s1, &c1);
                const float s2 = 2.f * s1 * c1, c2 = 1.f - 2.f * s1 * s1;
                const float s4 = 2.f * s2 * c2, c4 = 1.f - 2.f * s2 * s2;
                const float s8 = 2.f * s4 * c4, c8 = 1.f - 2.f * s4 * s4;
                pe[3 + c * 8 + 0] = s1; pe[3 + c * 8 + 1] = s2;
                pe[3 + c * 8 + 2] = s4; pe[3 + c * 8 + 3] = s8;
                pe[3 + c * 8 + 4] = c1; pe[3 + c * 8 + 5] = c2;
                pe[3 + c * 8 + 6] = c4; pe[3 + c * 8 + 7] = c8;
            }
            unsigned dw[16];
            #pragma unroll
            for (int j = 0; j < 14; ++j) dw[j] = pk2(pe[2 * j], pe[2 * j + 1]);
            dw[14] = 0u; dw[15] = 0u;
            #pragma unroll
            for (int kc = 0; kc < 4; ++kc) {
                uint4 v = make_uint4(dw[4 * kc + 0], dw[4 * kc + 1], dw[4 * kc + 2], dw[4 * kc + 3]);
                *(uint4*)(act + lane * 64 + ((kc ^ (lane & 3)) << 4)) = v;
            }

            f32x4 acc[4][4];
            // ---- L1: K=32 (1 k-step) ----
            {
                f16x8 bx[4];
                #pragma unroll
                for (int nt = 0; nt < 4; ++nt)
                    bx[nt] = *(const f16x8*)(act + (16 * nt + lh) * 64 + ((g ^ (lh & 3)) << 4));
                #pragma unroll
                for (int mt = 0; mt < 4; ++mt) {
                    const f32x4 bf = *(const f32x4*)&sB1[16 * mt + 4 * g];
                    const f16x8 a = *(const f16x8*)(sW1 + (16 * mt + lh) * 64 + ((g ^ (lh & 3)) << 4));
                    #pragma unroll
                    for (int nt = 0; nt < 4; ++nt)
                        acc[mt][nt] = __builtin_amdgcn_mfma_f32_16x16x32_f16(a, bx[nt], bf, 0, 0, 0);
                }
                // relu + pack -> H1 (rows 128B, swz (s&7))
                #pragma unroll
                for (int mt = 0; mt < 4; ++mt)
                #pragma unroll
                for (int nt = 0; nt < 4; ++nt) {
                    f32x4 c = acc[mt][nt];
                    c[0] = fmaxf(c[0], 0.f); c[1] = fmaxf(c[1], 0.f);
                    c[2] = fmaxf(c[2], 0.f); c[3] = fmaxf(c[3], 0.f);
                    uint2 v; v.x = pk2(c[0], c[1]); v.y = pk2(c[2], c[3]);
                    *(uint2*)(act + (16 * nt + lh) * 128 +
                              ((((2 * mt + (g >> 1)) ^ (lh & 7)) << 4)) + ((g & 1) << 3)) = v;
                }
            }
            // ---- L2: K=64 (2 k-steps) + sigma head ----
            float sp[4] = {0.f, 0.f, 0.f, 0.f};
            {
                #pragma unroll
                for (int mt = 0; mt < 4; ++mt) {
                    const f32x4 bf = *(const f32x4*)&sB2[16 * mt + 4 * g];
                    #pragma unroll
                    for (int nt = 0; nt < 4; ++nt) acc[mt][nt] = bf;
                }
                #pragma unroll
                for (int ks = 0; ks < 2; ++ks) {
                    f16x8 bh[4];
                    #pragma unroll
                    for (int nt = 0; nt < 4; ++nt)
                        bh[nt] = *(const f16x8*)(act + (16 * nt + lh) * 128 +
                                                 (((ks * 4 + g) ^ (lh & 7)) << 4));
                    #pragma unroll
                    for (int mt = 0; mt < 4; ++mt) {
                        const f16x8 a = *(const f16x8*)(sW2 + (16 * mt + lh) * 128 +
                                                        (((ks * 4 + g) ^ (lh & 7)) << 4));
                        #pragma unroll
                        for (int nt = 0; nt < 4; ++nt)
                            acc[mt][nt] = __builtin_amdgcn_mfma_f32_16x16x32_f16(a, bh[nt], acc[mt][nt], 0, 0, 0);
                    }
                }
                // relu + sigma partials + pack -> H2 (same layout as H1)
                #pragma unroll
                for (int mt = 0; mt < 4; ++mt) {
                    const f32x4 ws = *(const f32x4*)&sWs[16 * mt + 4 * g];
                    #pragma unroll
                    for (int nt = 0; nt < 4; ++nt) {
                        f32x4 c = acc[mt][nt];
                        c[0] = fmaxf(c[0], 0.f); c[1] = fmaxf(c[1], 0.f);
                        c[2] = fmaxf(c[2], 0.f); c[3] = fmaxf(c[3], 0.f);
                        sp[nt] += ws[0] * c[0] + ws[1] * c[1] + ws[2] * c[2] + ws[3] * c[3];
                        uint2 v; v.x = pk2(c[0], c[1]); v.y = pk2(c[2], c[3]);
                        *(uint2*)(act + (16 * nt + lh) * 128 +
                                  ((((2 * mt + (g >> 1)) ^ (lh & 7)) << 4)) + ((g & 1) << 3)) = v;
                    }
                }
            }
            // ---- Wc layer (init = pd + bc) + rgb head ----
            float cRp[4] = {0.f, 0.f, 0.f, 0.f}, cGp[4] = {0.f, 0.f, 0.f, 0.f}, cBp[4] = {0.f, 0.f, 0.f, 0.f};
            {
                #pragma unroll
                for (int mt = 0; mt < 4; ++mt) {
                    const f32x4 pdf = *(const f32x4*)&sPdB[wib][16 * mt + 4 * g];
                    #pragma unroll
                    for (int nt = 0; nt < 4; ++nt) acc[mt][nt] = pdf;
                }
                #pragma unroll
                for (int ks = 0; ks < 2; ++ks) {
                    f16x8 bh[4];
                    #pragma unroll
                    for (int nt = 0; nt < 4; ++nt)
                        bh[nt] = *(const f16x8*)(act + (16 * nt + lh) * 128 +
                                                 (((ks * 4 + g) ^ (lh & 7)) << 4));
                    #pragma unroll
                    for (int mt = 0; mt < 4; ++mt) {
                        const f16x8 a = *(const f16x8*)(sWc + (16 * mt + lh) * 128 +
                                                        (((ks * 4 + g) ^ (lh & 7)) << 4));
                        #pragma unroll
                        for (int nt = 0; nt < 4; ++nt)
                            acc[mt][nt] = __builtin_amdgcn_mfma_f32_16x16x32_f16(a, bh[nt], acc[mt][nt], 0, 0, 0);
                    }
                }
                #pragma unroll
                for (int mt = 0; mt < 4; ++mt) {
                    const f32x4 wr = *(const f32x4*)&sWrR[16 * mt + 4 * g];
                    const f32x4 wg = *(const f32x4*)&sWrG[16 * mt + 4 * g];
                    const f32x4 wb = *(const f32x4*)&sWrB[16 * mt + 4 * g];
                    #pragma unroll
                    for (int nt = 0; nt < 4; ++nt) {
                        f32x4 c = acc[mt][nt];
                        c[0] = fmaxf(c[0], 0.f); c[1] = fmaxf(c[1], 0.f);
                        c[2] = fmaxf(c[2], 0.f); c[3] = fmaxf(c[3], 0.f);
                        cRp[nt] += wr[0] * c[0] + wr[1] * c[1] + wr[2] * c[2] + wr[3] * c[3];
                        cGp[nt] += wg[0] * c[0] + wg[1] * c[1] + wg[2] * c[2] + wg[3] * c[3];
                        cBp[nt] += wb[0] * c[0] + wb[1] * c[1] + wb[2] * c[2] + wb[3] * c[3];
                    }
                }
            }
            // ---- cross-lane reduce heads (over g-groups) ----
            #pragma unroll
            for (int nt = 0; nt < 4; ++nt) {
                sp[nt]  += __shfl_xor(sp[nt], 16);  sp[nt]  += __shfl_xor(sp[nt], 32);
                cRp[nt] += __shfl_xor(cRp[nt], 16); cRp[nt] += __shfl_xor(cRp[nt], 32);
                cGp[nt] += __shfl_xor(cGp[nt], 16); cGp[nt] += __shfl_xor(cGp[nt], 32);
                cBp[nt] += __shfl_xor(cBp[nt], 16); cBp[nt] += __shfl_xor(cBp[nt], 32);
            }
            const float sgRaw = (g == 0) ? sp[0] : (g == 1) ? sp[1] : (g == 2) ? sp[2] : sp[3];
            const float crS   = (g == 0) ? cRp[0] : (g == 1) ? cRp[1] : (g == 2) ? cRp[2] : cRp[3];
            const float cgS   = (g == 0) ? cGp[0] : (g == 1) ? cGp[1] : (g == 2) ? cGp[2] : cGp[3];
            const float cbS   = (g == 0) ? cBp[0] : (g == 1) ? cBp[1] : (g == 2) ? cBp[2] : cBp[3];

            const float sigma = valid ? fmaxf(sgRaw + bsV, 0.f) : 0.f;
            const float rC = 1.f / (1.f + __expf(-(crS + br0)));
            const float gC = 1.f / (1.f + __expf(-(cgS + br1)));
            const float bC = 1.f / (1.f + __expf(-(cbS + br2)));

            // ---- compositing: wave inclusive scan ----
            const float sdelta = sigma * STEPf;
            float scan = sdelta;
            #pragma unroll
            for (int off = 1; off < 64; off <<= 1) {
                const float n = __shfl_up(scan, off);
                if (lane >= off) scan += n;
            }
            const float T     = __expf(-(carry + scan - sdelta));
            const float alpha = 1.f - __expf(-sdelta);
            const float w = T * alpha;
            aW  += w;
            aWT += w * t;
            aR  += w * rC;
            aG  += w * gC;
            aB  += w * bC;
            carry += __shfl(scan, 63);
            if (carry > 12.f) break;
        }
    }

    // ---- reduce across lanes + store ----
    #pragma unroll
    for (int off = 32; off; off >>= 1) {
        aW  += __shfl_xor(aW,  off);
        aWT += __shfl_xor(aWT, off);
        aR  += __shfl_xor(aR,  off);
        aG  += __shfl_xor(aG,  off);
        aB  += __shfl_xor(aB,  off);
    }
    if (lane == 0) {
        const float bg = 1.f - aW;
        out[ray * 3 + 0] = aR + bg;
        out[ray * 3 + 1] = aG + bg;
        out[ray * 3 + 2] = aB + bg;
        out[3 * nrays + ray] = aWT;
        out[4 * nrays + ray] = aW;
    }
}

extern "C" void kernel_launch(void* const* d_in, const int* in_sizes, int n_in,
                              void* d_out, int out_size, void* d_ws, size_t ws_size,
                              hipStream_t stream) {
    const float* rays_o   = (const float*)d_in[0];
    const float* viewdirs = (const float*)d_in[1];
    const void*  occ      = (const void*) d_in[2];
    const float* W1 = (const float*)d_in[3];
    const float* b1 = (const float*)d_in[4];
    const float* W2 = (const float*)d_in[5];
    const float* b2 = (const float*)d_in[6];
    const float* Ws = (const float*)d_in[7];
    const float* bs = (const float*)d_in[8];
    const float* Wc = (const float*)d_in[9];
    const float* Wd = (const float*)d_in[10];
    const float* bc = (const float*)d_in[11];
    const float* Wr = (const float*)d_in[12];
    const float* br = (const float*)d_in[13];
    float* out = (float*)d_out;

    const int nrays = in_sizes[0] / 3;
    const int nblocks = (nrays + 3) / 4;   // 4 rays (waves) per 256-thread block

    nerf_mfma<<<nblocks, 256, 0, stream>>>(rays_o, viewdirs, occ,
                                           W1, b1, W2, b2, Ws, bs, Wc, Wd, bc, Wr, br,
                                           out, nrays);
}